// Round 4
// baseline (2525.963 us; speedup 1.0000x reference)
//
#include <hip/hip_runtime.h>
#include <math.h>

// Fused Conv3d(3->16, k=3, valid) + bias + min over D + softmax over C.
// N=16, CIN=3, COUT=16, K=3, D=H=W=64 -> out [16,16,62,62] fp32.
//
// R7 (= R6 resubmit after infra failure, minus ~3 live VGPRs):
// R4 scalar compute (R5's packed-fp32 spilled: VGPR 256, +25MB scratch
// writes) but 4 pixels/thread instead of 8, tile 4h x 16w, grid 1024.
// R4 was latency-bound: real VALU issue util ~33% (VALUBusy's 67% is the
// gfx94x 2x-overcounting formula) at 2 waves/SIMD (VGPR=228). Halving
// per-thread state (A-ring 24->12, mv 8->4) drops architectural need to
// ~120 regs; __launch_bounds__(256,4) caps at 128 -> 4 waves/SIMD,
// 4 blocks/CU. Per-CU work unchanged; 4-way TLP hides LDS latency.
// Staging: double-buffered global_load_lds DMA, one barrier per chunk.
// Spill tripwires: VGPR<=128, WRITE_SIZE ~5.3MB.

#define CH 8  // d-slices per staged chunk

// apply taps (kh) for current (ci): 3 kw x 4 p x 3 kd FMAs on one row
#define TAPS(kh)                                                           \
    _Pragma("unroll")                                                      \
    for (int kw = 0; kw < 3; ++kw) {                                       \
        const float wk0 = wreg[ci * 27 + 0  + (kh) * 3 + kw];              \
        const float wk1 = wreg[ci * 27 + 9  + (kh) * 3 + kw];              \
        const float wk2 = wreg[ci * 27 + 18 + (kh) * 3 + kw];              \
        _Pragma("unroll")                                                  \
        for (int p = 0; p < 4; ++p) {                                      \
            const float xv = row[kw + p];                                  \
            A2[p] = fmaf(xv, wk0, A2[p]); /* d' = d   */                   \
            A1[p] = fmaf(xv, wk1, A1[p]); /* d' = d-1 */                   \
            A0[p] = fmaf(xv, wk2, A0[p]); /* d' = d-2 */                   \
        }                                                                  \
    }

__global__ __launch_bounds__(256, 4) void conv3d_min_softmax(
    const float* __restrict__ x,     // [16,3,64,64,64]
    const float* __restrict__ wgt,   // [16,3,3,3,3]
    const float* __restrict__ bias,  // [16]
    float* __restrict__ out)         // [16,16,62,62]
{
    const int tid = threadIdx.x;
    const int co  = tid & 15;          // output channel on lane bits 0..3
    const int s   = tid >> 4;          // 0..15 strip id
    const int R   = s >> 2;            // output row within tile (0..3)
    const int wc  = (s & 3) * 4;       // output cols wc..wc+3 (0,4,8,12)
    const int n   = blockIdx.z;
    const int h0  = blockIdx.y * 4;    // 16 h-tiles cover rows 0..63 (62 valid)
    const int w0  = blockIdx.x * 16;   // 4 w-tiles cover cols 0..63 (62 valid)

    // staged x, double-buffered. Logical layout per buffer:
    // [3 ci][CH dd][6 rows][20 cols] = 2880 floats (11520 B), padded to
    // 768 float4 (12288 B) so every thread issues exactly 3 DMAs.
    __shared__ __align__(16) float sx[2][768 * 4];

    // per-thread weights: idx = ci*27 + kd*9 + kh*3 + kw
    float wreg[81];
#pragma unroll
    for (int i = 0; i < 81; ++i) wreg[i] = wgt[co * 81 + i];

    // ---- hoisted staging address math (chunk 0, d0 = 0) ----
    // float4 slot F = tid + 256*k maps to LDS byte offset F*16 (lane-linear)
    // and global float index (((ci*64 + dd)*64 + gh)*64 + gw).
    int goff[3];  // global BYTE offsets for k = 0..2
#pragma unroll
    for (int k = 0; k < 3; ++k) {
        int F  = tid + 256 * k;
        int Fc = F < 720 ? F : 719;      // pad region: harmless dup fetch
        int rowid = Fc / 5;              // ci*(CH*6) + dd*6 + r
        int g     = Fc - rowid * 5;      // col group (4 floats)
        int ci    = rowid / (CH * 6);
        int rem   = rowid - ci * (CH * 6);
        int dd    = rem / 6;
        int r     = rem - dd * 6;
        int gh    = min(h0 + r, 63);     // clamp: edge halo, unused
        int gw    = min(w0 + g * 4, 60); // clamp: cols >=62 unused
        goff[k]   = (((ci * 64 + dd) * 64 + gh) * 64 + gw) * 4;
    }
    // prefetch source pointer, advanced by one chunk stride per iteration
    const char* xb = (const char*)(x + (size_t)n * 3 * 64 * 64 * 64);
    const char* xpre = xb + (size_t)(CH * 64 * 64 * 4);
    // LDS staging dest for this thread; buffer toggled via XOR of byte 12288
    char* lds = (char*)&sx[0][0] + tid * 16;

    // ring: A0 completes this step (kd=2), A1 next (kd=1), A2 after (kd=0)
    float A0[4], A1[4], A2[4], mv[4];
#pragma unroll
    for (int p = 0; p < 4; ++p) {
        A0[p] = A1[p] = A2[p] = 0.f;
        mv[p] = 1e30f;
    }

    // ---- issue chunk 0 DMA (into buffer 0) ----
#pragma unroll
    for (int k = 0; k < 3; ++k)
        __builtin_amdgcn_global_load_lds(
            (const void*)(xb + goff[k]), (void*)(lds + k * 4096), 16, 0, 0);

    for (int c = 0; c < 64 / CH; ++c) {
        // Drains vmcnt(0): chunk c's DMA has landed; all waves are done
        // reading the other buffer, so it is free to be overwritten below.
        __syncthreads();

        // ---- issue chunk c+1 DMA; flies during this chunk's compute ----
        if (c < 7) {
            char* ldsn = (char*)((size_t)lds ^ 12288u);  // other buffer
#pragma unroll
            for (int k = 0; k < 3; ++k)
                __builtin_amdgcn_global_load_lds(
                    (const void*)(xpre + goff[k]), (void*)(ldsn + k * 4096),
                    16, 0, 0);
            xpre += (size_t)(CH * 64 * 64 * 4);
            lds = ldsn;  // next iteration computes from what we just started
        }

        // compute reads the buffer whose DMA completed at the barrier:
        // that is the buffer 'lds' pointed to BEFORE the toggle above —
        // i.e. buffer (c&1). Recover it directly from c to keep the
        // dataflow simple for the scheduler.
        const float* S = sx[c & 1];
        const int d0 = c * CH;

        // ---- compute CH d-steps from LDS ----
#pragma unroll 1
        for (int dd = 0; dd < CH; ++dd) {
#pragma unroll
            for (int ci = 0; ci < 3; ++ci) {
#pragma unroll
                for (int kh = 0; kh < 3; ++kh) {
                    const int base =
                        (ci * (CH * 6) + dd * 6 + R + kh) * 20 + wc;
                    const float4 a = *(const float4*)&S[base];
                    const float2 b = *(const float2*)&S[base + 4];
                    const float row[6] = {a.x, a.y, a.z, a.w, b.x, b.y};
                    TAPS(kh)
                }
            }
            const int d = d0 + dd;
            if (d >= 2) {
#pragma unroll
                for (int p = 0; p < 4; ++p)
                    mv[p] = fminf(mv[p], A0[p]);
            }
#pragma unroll
            for (int p = 0; p < 4; ++p) {
                A0[p] = A1[p];
                A1[p] = A2[p];
                A2[p] = 0.f;
            }
        }
    }

    // ---- epilogue: bias, softmax over 16 channels (lanes), store ----
    const float bv = bias[co];
    const int hp = h0 + R;
#pragma unroll
    for (int p = 0; p < 4; ++p) {
        float v = mv[p] + bv;
        float mx = v;
#pragma unroll
        for (int off = 1; off < 16; off <<= 1)
            mx = fmaxf(mx, __shfl_xor(mx, off, 64));
        float e = __expf(v - mx);
        float sum = e;
#pragma unroll
        for (int off = 1; off < 16; off <<= 1)
            sum += __shfl_xor(sum, off, 64);
        const int wp = w0 + wc + p;
        if (hp < 62 && wp < 62)
            out[(((size_t)n * 16 + co) * 62 + hp) * 62 + wp] = e / sum;
    }
}

extern "C" void kernel_launch(void* const* d_in, const int* in_sizes, int n_in,
                              void* d_out, int out_size, void* d_ws, size_t ws_size,
                              hipStream_t stream) {
    const float* x    = (const float*)d_in[0];
    const float* wgt  = (const float*)d_in[1];
    const float* bias = (const float*)d_in[2];
    float* out        = (float*)d_out;
    dim3 grid(4, 16, 16);  // (w-tiles, h-tiles, n)
    dim3 block(256);
    hipLaunchKernelGGL(conv3d_min_softmax, grid, block, 0, stream,
                       x, wgt, bias, out);
}

// Round 5
// 307.705 us; speedup vs baseline: 8.2090x; 8.2090x over previous
//
#include <hip/hip_runtime.h>
#include <math.h>

// Fused Conv3d(3->16, k=3, valid) + bias + min over D + softmax over C.
// N=16, CIN=3, COUT=16, K=3, D=H=W=64 -> out [16,16,62,62] fp32.
//
// R8: R7 geometry (4 px/thread, tile 4h x 16w, grid 1024, double-buffered
// global_load_lds staging) with NO launch_bounds occupancy floor.
// R7's (256,4) floor made the compiler allocate 64 VGPRs and spill
// wreg[81] to scratch (WRITE_SIZE 5.3MB -> 320MB, FETCH 75MB -> 7.4GB,
// 10x regression). Twice-confirmed rule: explicit occupancy floors spill
// wreg[81] on this kernel. Here the allocator runs free; the hypothesis
// is that 4px/thread state (81 w + 12 ring + 4 mv + ~25 misc) naturally
// lands <=168 VGPR -> 3 waves/SIMD (vs R4's 228 -> 2), +50% TLP to hide
// LDS latency. Tripwires: VGPR (want <=168), WRITE_SIZE (~5.3MB = clean).

#define CH 8  // d-slices per staged chunk

// apply taps (kh) for current (ci): 3 kw x 4 p x 3 kd FMAs on one row
#define TAPS(kh)                                                           \
    _Pragma("unroll")                                                      \
    for (int kw = 0; kw < 3; ++kw) {                                       \
        const float wk0 = wreg[ci * 27 + 0  + (kh) * 3 + kw];              \
        const float wk1 = wreg[ci * 27 + 9  + (kh) * 3 + kw];              \
        const float wk2 = wreg[ci * 27 + 18 + (kh) * 3 + kw];              \
        _Pragma("unroll")                                                  \
        for (int p = 0; p < 4; ++p) {                                      \
            const float xv = row[kw + p];                                  \
            A2[p] = fmaf(xv, wk0, A2[p]); /* d' = d   */                   \
            A1[p] = fmaf(xv, wk1, A1[p]); /* d' = d-1 */                   \
            A0[p] = fmaf(xv, wk2, A0[p]); /* d' = d-2 */                   \
        }                                                                  \
    }

__global__ __launch_bounds__(256) void conv3d_min_softmax(
    const float* __restrict__ x,     // [16,3,64,64,64]
    const float* __restrict__ wgt,   // [16,3,3,3,3]
    const float* __restrict__ bias,  // [16]
    float* __restrict__ out)         // [16,16,62,62]
{
    const int tid = threadIdx.x;
    const int co  = tid & 15;          // output channel on lane bits 0..3
    const int s   = tid >> 4;          // 0..15 strip id
    const int R   = s >> 2;            // output row within tile (0..3)
    const int wc  = (s & 3) * 4;       // output cols wc..wc+3 (0,4,8,12)
    const int n   = blockIdx.z;
    const int h0  = blockIdx.y * 4;    // 16 h-tiles cover rows 0..63 (62 valid)
    const int w0  = blockIdx.x * 16;   // 4 w-tiles cover cols 0..63 (62 valid)

    // staged x, double-buffered. Logical layout per buffer:
    // [3 ci][CH dd][6 rows][20 cols] = 2880 floats (11520 B), padded to
    // 768 float4 (12288 B) so every thread issues exactly 3 DMAs.
    __shared__ __align__(16) float sx[2][768 * 4];

    // per-thread weights: idx = ci*27 + kd*9 + kh*3 + kw
    float wreg[81];
#pragma unroll
    for (int i = 0; i < 81; ++i) wreg[i] = wgt[co * 81 + i];

    // ---- hoisted staging address math (chunk 0, d0 = 0) ----
    // float4 slot F = tid + 256*k maps to LDS byte offset F*16 (lane-linear)
    // and global float index (((ci*64 + dd)*64 + gh)*64 + gw).
    int goff[3];  // global BYTE offsets for k = 0..2
#pragma unroll
    for (int k = 0; k < 3; ++k) {
        int F  = tid + 256 * k;
        int Fc = F < 720 ? F : 719;      // pad region: harmless dup fetch
        int rowid = Fc / 5;              // ci*(CH*6) + dd*6 + r
        int g     = Fc - rowid * 5;      // col group (4 floats)
        int ci    = rowid / (CH * 6);
        int rem   = rowid - ci * (CH * 6);
        int dd    = rem / 6;
        int r     = rem - dd * 6;
        int gh    = min(h0 + r, 63);     // clamp: edge halo, unused
        int gw    = min(w0 + g * 4, 60); // clamp: cols >=62 unused
        goff[k]   = (((ci * 64 + dd) * 64 + gh) * 64 + gw) * 4;
    }
    // prefetch source pointer, advanced by one chunk stride per iteration
    const char* xb = (const char*)(x + (size_t)n * 3 * 64 * 64 * 64);
    const char* xpre = xb + (size_t)(CH * 64 * 64 * 4);
    // LDS staging dest for this thread; buffer toggled via XOR of byte 12288
    char* lds = (char*)&sx[0][0] + tid * 16;

    // ring: A0 completes this step (kd=2), A1 next (kd=1), A2 after (kd=0)
    float A0[4], A1[4], A2[4], mv[4];
#pragma unroll
    for (int p = 0; p < 4; ++p) {
        A0[p] = A1[p] = A2[p] = 0.f;
        mv[p] = 1e30f;
    }

    // ---- issue chunk 0 DMA (into buffer 0) ----
#pragma unroll
    for (int k = 0; k < 3; ++k)
        __builtin_amdgcn_global_load_lds(
            (const void*)(xb + goff[k]), (void*)(lds + k * 4096), 16, 0, 0);

    for (int c = 0; c < 64 / CH; ++c) {
        // Drains vmcnt(0): chunk c's DMA has landed; all waves are done
        // reading the other buffer, so it is free to be overwritten below.
        __syncthreads();

        // ---- issue chunk c+1 DMA; flies during this chunk's compute ----
        if (c < 7) {
            char* ldsn = (char*)((size_t)lds ^ 12288u);  // other buffer
#pragma unroll
            for (int k = 0; k < 3; ++k)
                __builtin_amdgcn_global_load_lds(
                    (const void*)(xpre + goff[k]), (void*)(ldsn + k * 4096),
                    16, 0, 0);
            xpre += (size_t)(CH * 64 * 64 * 4);
            lds = ldsn;  // next iteration stages into the buffer just freed
        }

        // compute reads the buffer whose DMA completed at the barrier
        const float* S = sx[c & 1];
        const int d0 = c * CH;

        // ---- compute CH d-steps from LDS ----
#pragma unroll 1
        for (int dd = 0; dd < CH; ++dd) {
#pragma unroll
            for (int ci = 0; ci < 3; ++ci) {
#pragma unroll
                for (int kh = 0; kh < 3; ++kh) {
                    const int base =
                        (ci * (CH * 6) + dd * 6 + R + kh) * 20 + wc;
                    const float4 a = *(const float4*)&S[base];
                    const float2 b = *(const float2*)&S[base + 4];
                    const float row[6] = {a.x, a.y, a.z, a.w, b.x, b.y};
                    TAPS(kh)
                }
            }
            const int d = d0 + dd;
            if (d >= 2) {
#pragma unroll
                for (int p = 0; p < 4; ++p)
                    mv[p] = fminf(mv[p], A0[p]);
            }
#pragma unroll
            for (int p = 0; p < 4; ++p) {
                A0[p] = A1[p];
                A1[p] = A2[p];
                A2[p] = 0.f;
            }
        }
    }

    // ---- epilogue: bias, softmax over 16 channels (lanes), store ----
    const float bv = bias[co];
    const int hp = h0 + R;
#pragma unroll
    for (int p = 0; p < 4; ++p) {
        float v = mv[p] + bv;
        float mx = v;
#pragma unroll
        for (int off = 1; off < 16; off <<= 1)
            mx = fmaxf(mx, __shfl_xor(mx, off, 64));
        float e = __expf(v - mx);
        float sum = e;
#pragma unroll
        for (int off = 1; off < 16; off <<= 1)
            sum += __shfl_xor(sum, off, 64);
        const int wp = w0 + wc + p;
        if (hp < 62 && wp < 62)
            out[(((size_t)n * 16 + co) * 62 + hp) * 62 + wp] = e / sum;
    }
}

extern "C" void kernel_launch(void* const* d_in, const int* in_sizes, int n_in,
                              void* d_out, int out_size, void* d_ws, size_t ws_size,
                              hipStream_t stream) {
    const float* x    = (const float*)d_in[0];
    const float* wgt  = (const float*)d_in[1];
    const float* bias = (const float*)d_in[2];
    float* out        = (float*)d_out;
    dim3 grid(4, 16, 16);  // (w-tiles, h-tiles, n)
    dim3 block(256);
    hipLaunchKernelGGL(conv3d_min_softmax, grid, block, 0, stream,
                       x, wgt, bias, out);
}